// Round 10
// baseline (104.960 us; speedup 1.0000x reference)
//
#include <hip/hip_runtime.h>

#define T_LEN 32768
#define DIM   300
#define NCH   75     // DIM/4 float4 chunks per row
#define NP    5      // superdiagonal entries

__device__ __forceinline__ float fast_sigmoid(float z) {
    return 1.0f / (1.0f + __expf(-z));
}

// Each 16-lane group computes the 5 superdiagonal dot products for one t.
// No LDS, no barrier: w (6 KB total, shared by all 2048 blocks) stays
// L1/L2-resident; x gathers are issued first so their HBM latency is the
// only long pole. vals stored SoA: vals[i][t] = sigmoid(w_sd[i].x_t + b_sd[i])
__global__ __launch_bounds__(256, 8) void vals_kernel(
    const int*   __restrict__ doc,   // [T]
    const float* __restrict__ emb,   // [VOCAB, 300]
    const float* __restrict__ w,     // [6, 6, 300]
    const float* __restrict__ b,     // [6, 6]
    float*       __restrict__ vals)  // ws: [5][T]
{
    const int tid = threadIdx.x;
    const int g   = tid >> 4;       // group 0..15 -> one t each
    const int sub = tid & 15;
    const int t   = blockIdx.x * 16 + g;

    // ---- Issue the 5 long-latency gather loads first ----
    const float* __restrict__ xrow = emb + (size_t)doc[t] * DIM;
    const float4 x0 = *reinterpret_cast<const float4*>(xrow + 4 * (sub));
    const float4 x1 = *reinterpret_cast<const float4*>(xrow + 4 * (sub + 16));
    const float4 x2 = *reinterpret_cast<const float4*>(xrow + 4 * (sub + 32));
    const float4 x3 = *reinterpret_cast<const float4*>(xrow + 4 * (sub + 48));
    float4 x4 = make_float4(0.f, 0.f, 0.f, 0.f);
    if (sub < NCH - 64)
        x4 = *reinterpret_cast<const float4*>(xrow + 4 * (sub + 64));

    float a0 = 0.f, a1 = 0.f, a2 = 0.f, a3 = 0.f, a4 = 0.f;

    // w superdiagonal row i lives at flat row 7i+1 (stride 300 floats).
    // These reads are identical across all blocks -> L1/L2 broadcast hits.
    #define ACC(xv, c)                                                                  \
        {                                                                               \
            const float4 w0 = *reinterpret_cast<const float4*>(w + 1  * DIM + 4 * (c)); \
            const float4 w1 = *reinterpret_cast<const float4*>(w + 8  * DIM + 4 * (c)); \
            const float4 w2 = *reinterpret_cast<const float4*>(w + 15 * DIM + 4 * (c)); \
            const float4 w3 = *reinterpret_cast<const float4*>(w + 22 * DIM + 4 * (c)); \
            const float4 w4 = *reinterpret_cast<const float4*>(w + 29 * DIM + 4 * (c)); \
            a0 += (xv).x * w0.x + (xv).y * w0.y + (xv).z * w0.z + (xv).w * w0.w;        \
            a1 += (xv).x * w1.x + (xv).y * w1.y + (xv).z * w1.z + (xv).w * w1.w;        \
            a2 += (xv).x * w2.x + (xv).y * w2.y + (xv).z * w2.z + (xv).w * w2.w;        \
            a3 += (xv).x * w3.x + (xv).y * w3.y + (xv).z * w3.z + (xv).w * w3.w;        \
            a4 += (xv).x * w4.x + (xv).y * w4.y + (xv).z * w4.z + (xv).w * w4.w;        \
        }
    ACC(x0, sub);
    ACC(x1, sub + 16);
    ACC(x2, sub + 32);
    ACC(x3, sub + 48);
    if (sub < NCH - 64) ACC(x4, sub + 64);
    #undef ACC

    // 16-lane butterfly (xor offsets < 16 stay inside the group)
    #pragma unroll
    for (int off = 8; off >= 1; off >>= 1) {
        a0 += __shfl_xor(a0, off);
        a1 += __shfl_xor(a1, off);
        a2 += __shfl_xor(a2, off);
        a3 += __shfl_xor(a3, off);
        a4 += __shfl_xor(a4, off);
    }

    if (sub < NP) {
        const float a = (sub == 0) ? a0 : (sub == 1) ? a1 : (sub == 2) ? a2
                       : (sub == 3) ? a3 : a4;
        vals[sub * T_LEN + t] = fast_sigmoid(a + b[7 * sub + 1]);
    }
}

__global__ __launch_bounds__(256) void reduce_kernel(
    const float* __restrict__ vals,  // [5][T]
    float*       __restrict__ out)
{
    const int s = blockIdx.x * 256 + threadIdx.x;
    float p = 0.f;
    if (s <= T_LEN - NP) {
        p = vals[s]
          * vals[1 * T_LEN + s + 1]
          * vals[2 * T_LEN + s + 2]
          * vals[3 * T_LEN + s + 3]
          * vals[4 * T_LEN + s + 4];
    }
    #pragma unroll
    for (int off = 32; off >= 1; off >>= 1) p += __shfl_xor(p, off);

    __shared__ float partial[4];
    if ((threadIdx.x & 63) == 0) partial[threadIdx.x >> 6] = p;
    __syncthreads();
    if (threadIdx.x == 0)
        atomicAdd(out, partial[0] + partial[1] + partial[2] + partial[3]);
}

extern "C" void kernel_launch(void* const* d_in, const int* in_sizes, int n_in,
                              void* d_out, int out_size, void* d_ws, size_t ws_size,
                              hipStream_t stream) {
    const int*   doc = (const int*)  d_in[0];
    const float* emb = (const float*)d_in[1];
    const float* w   = (const float*)d_in[2];
    const float* b   = (const float*)d_in[3];
    float*       out = (float*)d_out;
    float*       vals = (float*)d_ws;   // 5*T*4 = 640 KB

    hipMemsetAsync(out, 0, sizeof(float), stream);

    vals_kernel<<<T_LEN / 16, 256, 0, stream>>>(doc, emb, w, b, vals);
    reduce_kernel<<<(T_LEN + 255) / 256, 256, 0, stream>>>(vals, out);
}